// Round 1
// baseline (3859.779 us; speedup 1.0000x reference)
//
#include <hip/hip_runtime.h>
#include <cstdint>
#include <cstddef>

// ---------------------------------------------------------------------------
// GNS model, restructured:
//   h = MLP_ne(x)
//   U = prelu(edge_attr@ee_w1 + ee_b1)            (recomputed on the fly, 4-wide input)
//   per layer l:
//     P = h@W1a ; Q = h@W1b ; R = h@Wn1a          (N-sized GEMMs)
//     z_e = U[e]@What_l + P[dst] + Q[src] + bvec_l ; t = prelu(z, le_a)
//     S = segment_sum(t, dst)                      (atomics)
//     V = prelu(R + S@Wtil_l + ln_b1 + deg*btil_l, ln_a)
//     h += V@ln_w2 + ln_b2
//   out = prelu(h@de_w1+de_b1)@de_w2 + de_b2
// where What = ee_w2@W1c, Wtil = le_w2@Wn1b, bvec = ee_b2@W1c + le_b1,
//       btil = le_b2@Wn1b  (precomputed on device once per call).
// ---------------------------------------------------------------------------

#define DEVI static __device__ __forceinline__

DEVI float4 ld4(const float* p) { return *(const float4*)p; }
DEVI void st4(float* p, float4 v) { *(float4*)p = v; }
DEVI float prelu1(float z, float a) { return z > 0.f ? z : a * z; }
DEVI void atomicAddF(float* p, float v) {
  __hip_atomic_fetch_add(p, v, __ATOMIC_RELAXED, __HIP_MEMORY_SCOPE_AGENT);
}

// ---------------------------------------------------------------------------
// Generic 128x128-tile fp32 GEMM core: out[M,128] = epi(A[M,128] @ W[128,128]).
// 256 threads, 8x8 per thread (rows {mg*4+i, 64+mg*4+i}, cols {ng*4+j, 64+ng*4+j})
// so all LDS reads are conflict-free b128 (2-way max, free per m136).
// ---------------------------------------------------------------------------
template<bool BIAS, bool PRELU, bool ADDMAT, bool DEGBIAS, bool RESID>
__device__ __forceinline__ void gemm128_core(
    const float* __restrict__ A, const float* __restrict__ W,
    float* __restrict__ out,
    const float* __restrict__ addmat, const float* __restrict__ bias,
    const float* __restrict__ bias2, const int* __restrict__ deg,
    const float* __restrict__ alpha_ptr, int M)
{
  __shared__ float As[128][132];   // As[k][m] = A[row0+m][k]
  __shared__ float Ws[128][132];   // Ws[k][n] = W[k][n]
  const int t = threadIdx.x;
  const int row0 = blockIdx.x * 128;

  #pragma unroll
  for (int it = 0; it < 16; ++it) {
    int idx = it * 256 + t;
    int m  = idx >> 5;
    int kc = (idx & 31) << 2;
    st4(&Ws[m][kc], ld4(W + m * 128 + kc));
    float4 av = make_float4(0.f, 0.f, 0.f, 0.f);
    int gr = row0 + m;
    if (gr < M) av = ld4(A + (size_t)gr * 128 + kc);
    As[kc + 0][m] = av.x;
    As[kc + 1][m] = av.y;
    As[kc + 2][m] = av.z;
    As[kc + 3][m] = av.w;
  }
  __syncthreads();

  float acc[8][8];
  #pragma unroll
  for (int i = 0; i < 8; ++i)
    #pragma unroll
    for (int j = 0; j < 8; ++j) acc[i][j] = 0.f;

  const int mg = t >> 4;
  const int ng = t & 15;
  const int m0 = mg * 4, m1 = 64 + mg * 4;
  const int n0 = ng * 4, n1 = 64 + ng * 4;

  #pragma unroll 4
  for (int k = 0; k < 128; ++k) {
    float4 a0 = ld4(&As[k][m0]);
    float4 a1 = ld4(&As[k][m1]);
    float4 w0 = ld4(&Ws[k][n0]);
    float4 w1 = ld4(&Ws[k][n1]);
    float aa[8] = {a0.x, a0.y, a0.z, a0.w, a1.x, a1.y, a1.z, a1.w};
    float ww[8] = {w0.x, w0.y, w0.z, w0.w, w1.x, w1.y, w1.z, w1.w};
    #pragma unroll
    for (int i = 0; i < 8; ++i)
      #pragma unroll
      for (int j = 0; j < 8; ++j)
        acc[i][j] = fmaf(aa[i], ww[j], acc[i][j]);
  }

  const float alpha = PRELU ? *alpha_ptr : 0.f;

  #pragma unroll
  for (int i = 0; i < 8; ++i) {
    int r = (i < 4) ? (m0 + i) : (m1 + (i - 4));
    int gr = row0 + r;
    if (gr >= M) continue;
    float degf = 0.f;
    if (DEGBIAS) degf = (float)deg[gr];
    #pragma unroll
    for (int half = 0; half < 2; ++half) {
      int nb = half ? n1 : n0;
      float z0 = acc[i][half * 4 + 0];
      float z1 = acc[i][half * 4 + 1];
      float z2 = acc[i][half * 4 + 2];
      float z3 = acc[i][half * 4 + 3];
      if (BIAS) {
        float4 bv = ld4(bias + nb);
        z0 += bv.x; z1 += bv.y; z2 += bv.z; z3 += bv.w;
      }
      if (ADDMAT) {
        float4 mv = ld4(addmat + (size_t)gr * 128 + nb);
        z0 += mv.x; z1 += mv.y; z2 += mv.z; z3 += mv.w;
      }
      if (DEGBIAS) {
        float4 b2v = ld4(bias2 + nb);
        z0 = fmaf(degf, b2v.x, z0); z1 = fmaf(degf, b2v.y, z1);
        z2 = fmaf(degf, b2v.z, z2); z3 = fmaf(degf, b2v.w, z3);
      }
      if (PRELU) {
        z0 = prelu1(z0, alpha); z1 = prelu1(z1, alpha);
        z2 = prelu1(z2, alpha); z3 = prelu1(z3, alpha);
      }
      float* op = out + (size_t)gr * 128 + nb;
      if (RESID) {
        float4 ov = ld4(op);
        z0 += ov.x; z1 += ov.y; z2 += ov.z; z3 += ov.w;
      }
      st4(op, make_float4(z0, z1, z2, z3));
    }
  }
}

template<bool BIAS, bool PRELU, bool ADDMAT, bool DEGBIAS, bool RESID>
__global__ __launch_bounds__(256, 1) void k_gemm(
    const float* __restrict__ A, const float* __restrict__ W, float* __restrict__ out,
    const float* __restrict__ addmat, const float* __restrict__ bias,
    const float* __restrict__ bias2, const int* __restrict__ deg,
    const float* __restrict__ alpha_ptr, int M)
{
  gemm128_core<BIAS, PRELU, ADDMAT, DEGBIAS, RESID>(A, W, out, addmat, bias, bias2,
                                                    deg, alpha_ptr, M);
}

// P/Q/R in one launch: blockIdx.y selects weight block and output buffer.
__global__ __launch_bounds__(256, 1) void k_pqr(
    const float* __restrict__ h, const float* __restrict__ le_w1_l,
    const float* __restrict__ ln_w1_l,
    float* __restrict__ P, float* __restrict__ Q, float* __restrict__ R, int M)
{
  const float* W; float* O;
  if (blockIdx.y == 0)      { W = le_w1_l;             O = P; }  // W1a (dst)
  else if (blockIdx.y == 1) { W = le_w1_l + 128 * 128; O = Q; }  // W1b (src)
  else                      { W = ln_w1_l;             O = R; }  // Wn1a
  gemm128_core<false, false, false, false, false>(h, W, O, nullptr, nullptr, nullptr,
                                                  nullptr, nullptr, M);
}

// ---------------------------------------------------------------------------
// Fused edge kernel: stages u-tile (recomputed from 4-wide edge_attr) and What
// into LDS, does the 128x128 GEMM, then epilogue: + P[dst] + Q[src] + bvec,
// PReLU, atomic scatter into S[dst].
// ---------------------------------------------------------------------------
__global__ __launch_bounds__(256, 1) void k_edge(
    const float* __restrict__ ea, const float* __restrict__ ee_w1,
    const float* __restrict__ ee_b1, const float* __restrict__ ee_a,
    const float* __restrict__ What, const float* __restrict__ bvec,
    const float* __restrict__ alpha_ptr,
    const float* __restrict__ P, const float* __restrict__ Q,
    const int* __restrict__ srcIdx, const int* __restrict__ dstIdx,
    float* __restrict__ S, int E)
{
  __shared__ float As[128][132];   // As[k][m] = u[e0+m][k]
  __shared__ float Ws[128][132];
  const int t = threadIdx.x;
  const int e0 = blockIdx.x * 128;

  #pragma unroll
  for (int it = 0; it < 16; ++it) {
    int idx = it * 256 + t;
    int m  = idx >> 5;
    int kc = (idx & 31) << 2;
    st4(&Ws[m][kc], ld4(What + m * 128 + kc));
  }
  {
    const int kc = (t & 31) << 2;     // fixed per thread
    const float ua = *ee_a;
    float4 w10 = ld4(ee_w1 + 0 * 128 + kc);
    float4 w11 = ld4(ee_w1 + 1 * 128 + kc);
    float4 w12 = ld4(ee_w1 + 2 * 128 + kc);
    float4 w13 = ld4(ee_w1 + 3 * 128 + kc);
    float4 b1c = ld4(ee_b1 + kc);
    #pragma unroll
    for (int it = 0; it < 16; ++it) {
      int m = it * 8 + (t >> 5);
      int ed = e0 + m;
      float4 eav = make_float4(0.f, 0.f, 0.f, 0.f);
      if (ed < E) eav = ld4(ea + (size_t)ed * 4);
      float ux = b1c.x, uy = b1c.y, uz = b1c.z, uw = b1c.w;
      ux = fmaf(eav.x, w10.x, ux); uy = fmaf(eav.x, w10.y, uy);
      uz = fmaf(eav.x, w10.z, uz); uw = fmaf(eav.x, w10.w, uw);
      ux = fmaf(eav.y, w11.x, ux); uy = fmaf(eav.y, w11.y, uy);
      uz = fmaf(eav.y, w11.z, uz); uw = fmaf(eav.y, w11.w, uw);
      ux = fmaf(eav.z, w12.x, ux); uy = fmaf(eav.z, w12.y, uy);
      uz = fmaf(eav.z, w12.z, uz); uw = fmaf(eav.z, w12.w, uw);
      ux = fmaf(eav.w, w13.x, ux); uy = fmaf(eav.w, w13.y, uy);
      uz = fmaf(eav.w, w13.z, uz); uw = fmaf(eav.w, w13.w, uw);
      As[kc + 0][m] = prelu1(ux, ua);
      As[kc + 1][m] = prelu1(uy, ua);
      As[kc + 2][m] = prelu1(uz, ua);
      As[kc + 3][m] = prelu1(uw, ua);
    }
  }
  __syncthreads();

  float acc[8][8];
  #pragma unroll
  for (int i = 0; i < 8; ++i)
    #pragma unroll
    for (int j = 0; j < 8; ++j) acc[i][j] = 0.f;

  const int mg = t >> 4;
  const int ng = t & 15;
  const int m0 = mg * 4, m1 = 64 + mg * 4;
  const int n0 = ng * 4, n1 = 64 + ng * 4;

  #pragma unroll 4
  for (int k = 0; k < 128; ++k) {
    float4 a0 = ld4(&As[k][m0]);
    float4 a1 = ld4(&As[k][m1]);
    float4 w0 = ld4(&Ws[k][n0]);
    float4 w1 = ld4(&Ws[k][n1]);
    float aa[8] = {a0.x, a0.y, a0.z, a0.w, a1.x, a1.y, a1.z, a1.w};
    float ww[8] = {w0.x, w0.y, w0.z, w0.w, w1.x, w1.y, w1.z, w1.w};
    #pragma unroll
    for (int i = 0; i < 8; ++i)
      #pragma unroll
      for (int j = 0; j < 8; ++j)
        acc[i][j] = fmaf(aa[i], ww[j], acc[i][j]);
  }

  const float alpha = *alpha_ptr;
  #pragma unroll
  for (int i = 0; i < 8; ++i) {
    int r = (i < 4) ? (m0 + i) : (m1 + (i - 4));
    int ed = e0 + r;
    if (ed >= E) continue;
    int d = dstIdx[ed];
    int s = srcIdx[ed];
    const float* Pr = P + (size_t)d * 128;
    const float* Qr = Q + (size_t)s * 128;
    float* Sr = S + (size_t)d * 128;
    #pragma unroll
    for (int half = 0; half < 2; ++half) {
      int nb = half ? n1 : n0;
      float4 pv = ld4(Pr + nb);
      float4 qv = ld4(Qr + nb);
      float4 bv = ld4(bvec + nb);
      float z0 = acc[i][half * 4 + 0] + pv.x + qv.x + bv.x;
      float z1 = acc[i][half * 4 + 1] + pv.y + qv.y + bv.y;
      float z2 = acc[i][half * 4 + 2] + pv.z + qv.z + bv.z;
      float z3 = acc[i][half * 4 + 3] + pv.w + qv.w + bv.w;
      z0 = prelu1(z0, alpha); z1 = prelu1(z1, alpha);
      z2 = prelu1(z2, alpha); z3 = prelu1(z3, alpha);
      atomicAddF(Sr + nb + 0, z0);
      atomicAddF(Sr + nb + 1, z1);
      atomicAddF(Sr + nb + 2, z2);
      atomicAddF(Sr + nb + 3, z3);
    }
  }
}

// ---------------------------------------------------------------------------
// Precompute folded weights: What_l = ee_w2@W1c_l, bvec_l = ee_b2@W1c_l + le_b1_l
//                            Wtil_l = le_w2_l@Wn1b_l, btil_l = le_b2_l@Wn1b_l
// ---------------------------------------------------------------------------
__global__ __launch_bounds__(256) void k_prep(
    const float* __restrict__ ee_w2, const float* __restrict__ ee_b2,
    const float* __restrict__ le_w1, const float* __restrict__ le_b1,
    const float* __restrict__ le_w2, const float* __restrict__ le_b2,
    const float* __restrict__ ln_w1,
    float* __restrict__ What, float* __restrict__ Wtil,
    float* __restrict__ bvec, float* __restrict__ btil)
{
  const int l = blockIdx.x;
  const int which = blockIdx.y;
  const float* L; const float* Rm; const float* lb; const float* badd;
  float* Wout; float* bout;
  if (which == 0) {
    L = ee_w2; Rm = le_w1 + (size_t)l * 384 * 128 + 256 * 128;
    lb = ee_b2; badd = le_b1 + l * 128;
    Wout = What + l * 16384; bout = bvec + l * 128;
  } else {
    L = le_w2 + (size_t)l * 16384; Rm = ln_w1 + (size_t)l * 256 * 128 + 128 * 128;
    lb = le_b2 + l * 128; badd = nullptr;
    Wout = Wtil + l * 16384; bout = btil + l * 128;
  }
  const int t = threadIdx.x;
  for (int eidx = t; eidx < 16384; eidx += 256) {
    int k = eidx >> 7, n = eidx & 127;
    float a = 0.f;
    for (int d = 0; d < 128; d += 4) {
      float4 lv = ld4(L + k * 128 + d);
      a = fmaf(lv.x, Rm[(d + 0) * 128 + n], a);
      a = fmaf(lv.y, Rm[(d + 1) * 128 + n], a);
      a = fmaf(lv.z, Rm[(d + 2) * 128 + n], a);
      a = fmaf(lv.w, Rm[(d + 3) * 128 + n], a);
    }
    Wout[eidx] = a;
  }
  if (t < 128) {
    float a = badd ? badd[t] : 0.f;
    for (int d = 0; d < 128; ++d) a = fmaf(lb[d], Rm[d * 128 + t], a);
    bout[t] = a;
  }
}

// First node-encoder layer: U = prelu(x@ne_w1 + ne_b1). One thread per 4 cols.
__global__ __launch_bounds__(256) void k_node_u(
    const float* __restrict__ x, const float* __restrict__ w1,
    const float* __restrict__ b1, const float* __restrict__ a_ptr,
    float* __restrict__ U, int M)
{
  int gid = blockIdx.x * 256 + threadIdx.x;
  int m = gid >> 5;
  if (m >= M) return;
  int nc = (gid & 31) << 2;
  float a = *a_ptr;
  float4 bb = ld4(b1 + nc);
  float z0 = bb.x, z1 = bb.y, z2 = bb.z, z3 = bb.w;
  const float* xr = x + (size_t)m * 30;
  #pragma unroll
  for (int j = 0; j < 30; ++j) {
    float xv = xr[j];
    float4 wv = ld4(w1 + j * 128 + nc);
    z0 = fmaf(xv, wv.x, z0); z1 = fmaf(xv, wv.y, z1);
    z2 = fmaf(xv, wv.z, z2); z3 = fmaf(xv, wv.w, z3);
  }
  st4(U + (size_t)m * 128 + nc,
      make_float4(prelu1(z0, a), prelu1(z1, a), prelu1(z2, a), prelu1(z3, a)));
}

__global__ void k_hist(const int* __restrict__ dstIdx, int* __restrict__ deg, int E) {
  int i = blockIdx.x * 256 + threadIdx.x;
  if (i < E) atomicAdd(deg + dstIdx[i], 1);
}

// Decoder second layer: out[M,3] = V@de_w2 + de_b2, V-tile staged in LDS.
__global__ __launch_bounds__(256) void k_dec2(
    const float* __restrict__ V, const float* __restrict__ w2,
    const float* __restrict__ b2, float* __restrict__ out, int M)
{
  __shared__ float Vt[64][132];
  __shared__ float w2s[384];
  const int t = threadIdx.x;
  const int row0 = blockIdx.x * 64;
  for (int i = t; i < 384; i += 256) w2s[i] = w2[i];
  #pragma unroll
  for (int it = 0; it < 8; ++it) {
    int idx = it * 256 + t;
    int m  = idx >> 5;
    int kc = (idx & 31) << 2;
    float4 v = make_float4(0.f, 0.f, 0.f, 0.f);
    if (row0 + m < M) v = ld4(V + (size_t)(row0 + m) * 128 + kc);
    st4(&Vt[m][kc], v);
  }
  __syncthreads();
  if (t < 192) {
    int m = t / 3, j = t - 3 * (t / 3);
    if (row0 + m < M) {
      float a = b2[j];
      for (int k = 0; k < 128; ++k) a = fmaf(Vt[m][k], w2s[k * 3 + j], a);
      out[(size_t)(row0 + m) * 3 + j] = a;
    }
  }
}

// ---------------------------------------------------------------------------
extern "C" void kernel_launch(void* const* d_in, const int* in_sizes, int n_in,
                              void* d_out, int out_size, void* d_ws, size_t ws_size,
                              hipStream_t stream)
{
  const float* x     = (const float*)d_in[0];
  const float* ea    = (const float*)d_in[1];
  const int*   ei    = (const int*)  d_in[2];
  const float* ne_w1 = (const float*)d_in[3];
  const float* ne_b1 = (const float*)d_in[4];
  const float* ne_a  = (const float*)d_in[5];
  const float* ne_w2 = (const float*)d_in[6];
  const float* ne_b2 = (const float*)d_in[7];
  const float* ee_w1 = (const float*)d_in[8];
  const float* ee_b1 = (const float*)d_in[9];
  const float* ee_a  = (const float*)d_in[10];
  const float* ee_w2 = (const float*)d_in[11];
  const float* ee_b2 = (const float*)d_in[12];
  const float* le_w1 = (const float*)d_in[13];
  const float* le_b1 = (const float*)d_in[14];
  const float* le_a  = (const float*)d_in[15];
  const float* le_w2 = (const float*)d_in[16];
  const float* le_b2 = (const float*)d_in[17];
  const float* ln_w1 = (const float*)d_in[18];
  const float* ln_b1 = (const float*)d_in[19];
  const float* ln_a  = (const float*)d_in[20];
  const float* ln_w2 = (const float*)d_in[21];
  const float* ln_b2 = (const float*)d_in[22];
  const float* de_w1 = (const float*)d_in[23];
  const float* de_b1 = (const float*)d_in[24];
  const float* de_a  = (const float*)d_in[25];
  const float* de_w2 = (const float*)d_in[26];
  const float* de_b2 = (const float*)d_in[27];

  const int N = in_sizes[0] / 30;
  const int E = in_sizes[1] / 4;
  const int* srcIdx = ei;        // edge_index[0] = x_j
  const int* dstIdx = ei + E;    // edge_index[1] = x_i / aggregation index

  float* w = (float*)d_ws;
  const size_t NN = (size_t)N * 128;
  float* h    = w; w += NN;
  float* Pb   = w; w += NN;
  float* Qb   = w; w += NN;
  float* Rb   = w; w += NN;
  float* Sb   = w; w += NN;
  float* Vb   = w; w += NN;   // also reused as UN (node-encoder hidden)
  float* What = w; w += 5 * 16384;
  float* Wtil = w; w += 5 * 16384;
  float* bvec = w; w += 5 * 128;
  float* btil = w; w += 5 * 128;
  int*   deg  = (int*)w;

  float* out = (float*)d_out;
  const int gN = (N + 127) / 128;
  const int gE = (E + 127) / 128;

  // Folded weights (10 small 128^3 GEMMs + bias vectors)
  k_prep<<<dim3(5, 2), dim3(256), 0, stream>>>(ee_w2, ee_b2, le_w1, le_b1,
                                               le_w2, le_b2, ln_w1,
                                               What, Wtil, bvec, btil);
  // Node encoder: UN (in Vb) then h
  k_node_u<<<dim3((N * 32 + 255) / 256), dim3(256), 0, stream>>>(x, ne_w1, ne_b1, ne_a, Vb, N);
  k_gemm<true, false, false, false, false><<<dim3(gN), dim3(256), 0, stream>>>(
      Vb, ne_w2, h, nullptr, ne_b2, nullptr, nullptr, nullptr, N);
  // Degree histogram
  hipMemsetAsync(deg, 0, (size_t)N * 4, stream);
  k_hist<<<dim3((E + 255) / 256), dim3(256), 0, stream>>>(dstIdx, deg, E);

  for (int l = 0; l < 5; ++l) {
    k_pqr<<<dim3(gN, 3), dim3(256), 0, stream>>>(
        h, le_w1 + (size_t)l * 384 * 128, ln_w1 + (size_t)l * 256 * 128, Pb, Qb, Rb, N);
    hipMemsetAsync(Sb, 0, NN * 4, stream);
    k_edge<<<dim3(gE), dim3(256), 0, stream>>>(
        ea, ee_w1, ee_b1, ee_a, What + l * 16384, bvec + l * 128, le_a + l,
        Pb, Qb, srcIdx, dstIdx, Sb, E);
    k_gemm<true, true, true, true, false><<<dim3(gN), dim3(256), 0, stream>>>(
        Sb, Wtil + l * 16384, Vb, Rb, ln_b1 + (size_t)l * 128, btil + l * 128,
        deg, ln_a + l, N);
    k_gemm<true, false, false, false, true><<<dim3(gN), dim3(256), 0, stream>>>(
        Vb, ln_w2 + (size_t)l * 16384, h, nullptr, ln_b2 + (size_t)l * 128,
        nullptr, nullptr, nullptr, N);
  }

  // Decoder
  k_gemm<true, true, false, false, false><<<dim3(gN), dim3(256), 0, stream>>>(
      h, de_w1, Vb, nullptr, de_b1, nullptr, nullptr, de_a, N);
  k_dec2<<<dim3((N + 63) / 64), dim3(256), 0, stream>>>(Vb, de_w2, de_b2, out, N);
}

// Round 2
// 1650.051 us; speedup vs baseline: 2.3392x; 2.3392x over previous
//
#include <hip/hip_runtime.h>
#include <cstdint>
#include <cstddef>

// ---------------------------------------------------------------------------
// GNS model, restructured + dst-sorted aggregation:
//   sort edges by dst (counting sort, on device each call)
//   h = MLP_ne(x)
//   per layer l:
//     P = h@W1a ; Q = h@W1b                       (N-GEMMs)
//     z_e = U[e]@What_l + P[dst] + Q[src] + bvec_l ; t = prelu(z, le_a)
//     S = segment_sum(t, dst)   -- register run-accumulation over sorted dst,
//                                  few atomics (only run boundaries)
//     V = prelu(S@Wtil_l + h@Wn1a_l + ln_b1 + deg*btil_l, ln_a)   \ fused in
//     h = h + V@ln_w2_l + ln_b2                                    / one kernel
//   out = prelu(h@de_w1+de_b1)@de_w2 + de_b2      (fused decoder)
// What = ee_w2@W1c, Wtil = le_w2@Wn1b, bvec = ee_b2@W1c + le_b1,
// btil = le_b2@Wn1b  (folded on device; U = prelu(ea@ee_w1+ee_b1) recomputed
// on the fly from the 4-wide edge input).
// All GEMM kernels: 128x128 tile, K chunked in 2x64 so LDS = 65 KB -> 2 blocks/CU.
// ---------------------------------------------------------------------------

#define DEVI static __device__ __forceinline__

DEVI float4 ld4(const float* p) { return *(const float4*)p; }
DEVI void st4(float* p, float4 v) { *(float4*)p = v; }
DEVI float prelu1(float z, float a) { return z > 0.f ? z : a * z; }
DEVI void atomicAddF(float* p, float v) {
  __hip_atomic_fetch_add(p, v, __ATOMIC_RELAXED, __HIP_MEMORY_SCOPE_AGENT);
}

// Thread (of 256) owns rows r0..r0+7 (r0=(t>>4)*8, consecutive for run-reduce)
// and cols n0..n0+3, n1..n1+3 (n0=(t&15)*4, n1=n0+64).
// acc[i][j]: j<4 -> col n0+j ; j>=4 -> col n1+(j-4).

DEVI void kloop64(const float (*As)[132], const float (*Ws)[128],
                  float acc[8][8], int r0, int n0, int n1)
{
  #pragma unroll 4
  for (int k = 0; k < 64; ++k) {
    float4 a0 = ld4(&As[k][r0]);
    float4 a1 = ld4(&As[k][r0 + 4]);
    float4 w0 = ld4(&Ws[k][n0]);
    float4 w1 = ld4(&Ws[k][n1]);
    float aa[8] = {a0.x, a0.y, a0.z, a0.w, a1.x, a1.y, a1.z, a1.w};
    float ww[8] = {w0.x, w0.y, w0.z, w0.w, w1.x, w1.y, w1.z, w1.w};
    #pragma unroll
    for (int i = 0; i < 8; ++i)
      #pragma unroll
      for (int j = 0; j < 8; ++j)
        acc[i][j] = fmaf(aa[i], ww[j], acc[i][j]);
  }
}

// One K-chunk (64) of out += A[row0:row0+128, c*64:c*64+64] @ W[c*64:.., 0:128]
DEVI void gemm_chunk(const float* __restrict__ A, const float* __restrict__ W,
                     int c, int row0, int M, int t,
                     float (*As)[132], float (*Ws)[128], float acc[8][8])
{
  #pragma unroll
  for (int it = 0; it < 8; ++it) {
    int idx = it * 256 + t;
    int k = idx >> 5, nc = (idx & 31) << 2;
    st4(&Ws[k][nc], ld4(W + (size_t)(c * 64 + k) * 128 + nc));
  }
  #pragma unroll
  for (int it = 0; it < 8; ++it) {
    int idx = it * 256 + t;
    int m = idx >> 4, kc = (idx & 15) << 2;
    int gr = row0 + m;
    float4 av = make_float4(0.f, 0.f, 0.f, 0.f);
    if (gr < M) av = ld4(A + (size_t)gr * 128 + c * 64 + kc);
    As[kc + 0][m] = av.x; As[kc + 1][m] = av.y;
    As[kc + 2][m] = av.z; As[kc + 3][m] = av.w;
  }
  __syncthreads();
  kloop64(As, Ws, acc, (threadIdx.x >> 4) * 8, (threadIdx.x & 15) * 4,
          64 + (threadIdx.x & 15) * 4);
  __syncthreads();
}

// Generic GEMM: out = [prelu](A@W [+bias])
template<bool BIAS, bool PRELU>
__global__ __launch_bounds__(256, 2) void k_gemm(
    const float* __restrict__ A, const float* __restrict__ W,
    float* __restrict__ out, const float* __restrict__ bias,
    const float* __restrict__ alpha_ptr, int M)
{
  __shared__ float As[64][132];
  __shared__ float Ws[64][128];
  const int t = threadIdx.x;
  const int row0 = blockIdx.x * 128;
  float acc[8][8];
  #pragma unroll
  for (int i = 0; i < 8; ++i)
    #pragma unroll
    for (int j = 0; j < 8; ++j) acc[i][j] = 0.f;
  for (int c = 0; c < 2; ++c) gemm_chunk(A, W, c, row0, M, t, As, Ws, acc);

  const int r0 = (t >> 4) * 8, n0 = (t & 15) * 4, n1 = 64 + n0;
  const float alpha = PRELU ? *alpha_ptr : 0.f;
  float4 b0 = make_float4(0.f,0.f,0.f,0.f), b1 = b0;
  if (BIAS) { b0 = ld4(bias + n0); b1 = ld4(bias + n1); }
  #pragma unroll
  for (int i = 0; i < 8; ++i) {
    int gr = row0 + r0 + i;
    if (gr >= M) continue;
    float z[8];
    z[0]=acc[i][0]+b0.x; z[1]=acc[i][1]+b0.y; z[2]=acc[i][2]+b0.z; z[3]=acc[i][3]+b0.w;
    z[4]=acc[i][4]+b1.x; z[5]=acc[i][5]+b1.y; z[6]=acc[i][6]+b1.z; z[7]=acc[i][7]+b1.w;
    if (PRELU) {
      #pragma unroll
      for (int j = 0; j < 8; ++j) z[j] = prelu1(z[j], alpha);
    }
    float* op = out + (size_t)gr * 128;
    st4(op + n0, make_float4(z[0], z[1], z[2], z[3]));
    st4(op + n1, make_float4(z[4], z[5], z[6], z[7]));
  }
}

// P and Q in one dispatch (blockIdx.y selects the 128-row slice of le_w1).
__global__ __launch_bounds__(256, 2) void k_pq(
    const float* __restrict__ h, const float* __restrict__ le_w1_l,
    float* __restrict__ P, float* __restrict__ Q, int M)
{
  __shared__ float As[64][132];
  __shared__ float Ws[64][128];
  const int t = threadIdx.x;
  const int row0 = blockIdx.x * 128;
  const float* W = le_w1_l + (size_t)blockIdx.y * 16384;
  float* O = blockIdx.y ? Q : P;
  float acc[8][8];
  #pragma unroll
  for (int i = 0; i < 8; ++i)
    #pragma unroll
    for (int j = 0; j < 8; ++j) acc[i][j] = 0.f;
  for (int c = 0; c < 2; ++c) gemm_chunk(h, W, c, row0, M, t, As, Ws, acc);
  const int r0 = (t >> 4) * 8, n0 = (t & 15) * 4, n1 = 64 + n0;
  #pragma unroll
  for (int i = 0; i < 8; ++i) {
    int gr = row0 + r0 + i;
    if (gr >= M) continue;
    float* op = O + (size_t)gr * 128;
    st4(op + n0, make_float4(acc[i][0], acc[i][1], acc[i][2], acc[i][3]));
    st4(op + n1, make_float4(acc[i][4], acc[i][5], acc[i][6], acc[i][7]));
  }
}

DEVI void flush8(float* __restrict__ S, int d, int n0, int n1, float4 sa, float4 sb)
{
  float* p = S + (size_t)d * 128;
  atomicAddF(p + n0 + 0, sa.x); atomicAddF(p + n0 + 1, sa.y);
  atomicAddF(p + n0 + 2, sa.z); atomicAddF(p + n0 + 3, sa.w);
  atomicAddF(p + n1 + 0, sb.x); atomicAddF(p + n1 + 1, sb.y);
  atomicAddF(p + n1 + 2, sb.z); atomicAddF(p + n1 + 3, sb.w);
}

// Fused edge kernel over dst-SORTED edges: recompute U-tile into LDS, GEMM with
// What, epilogue adds P[dst]+Q[src]+bvec, prelu, run-accumulates equal-dst rows
// in registers, flushes runs with atomics.
__global__ __launch_bounds__(256, 2) void k_edge(
    const float* __restrict__ sEa, const int* __restrict__ sSrc,
    const int* __restrict__ sDst,
    const float* __restrict__ ee_w1, const float* __restrict__ ee_b1,
    const float* __restrict__ ee_a,
    const float* __restrict__ What, const float* __restrict__ bvec,
    const float* __restrict__ alpha_ptr,
    const float* __restrict__ P, const float* __restrict__ Q,
    float* __restrict__ S, int E)
{
  __shared__ float As[64][132];
  __shared__ float Ws[64][128];
  const int t = threadIdx.x;
  const int e0 = blockIdx.x * 128;
  const float ua = *ee_a;
  float acc[8][8];
  #pragma unroll
  for (int i = 0; i < 8; ++i)
    #pragma unroll
    for (int j = 0; j < 8; ++j) acc[i][j] = 0.f;

  const int r0 = (t >> 4) * 8, n0 = (t & 15) * 4, n1 = 64 + n0;

  for (int c = 0; c < 2; ++c) {
    #pragma unroll
    for (int it = 0; it < 8; ++it) {
      int idx = it * 256 + t;
      int k = idx >> 5, nc = (idx & 31) << 2;
      st4(&Ws[k][nc], ld4(What + (size_t)(c * 64 + k) * 128 + nc));
    }
    {
      const int kc2 = (t & 15) << 2;
      float4 w0 = ld4(ee_w1 + 0 * 128 + c * 64 + kc2);
      float4 w1 = ld4(ee_w1 + 1 * 128 + c * 64 + kc2);
      float4 w2 = ld4(ee_w1 + 2 * 128 + c * 64 + kc2);
      float4 w3 = ld4(ee_w1 + 3 * 128 + c * 64 + kc2);
      float4 bb = ld4(ee_b1 + c * 64 + kc2);
      #pragma unroll
      for (int i = 0; i < 8; ++i) {
        int m = (t >> 4) * 8 + i;
        int ed = e0 + m;
        float4 eav = make_float4(0.f, 0.f, 0.f, 0.f);
        if (ed < E) eav = ld4(sEa + (size_t)ed * 4);
        float ux = bb.x, uy = bb.y, uz = bb.z, uw = bb.w;
        ux = fmaf(eav.x, w0.x, ux); uy = fmaf(eav.x, w0.y, uy);
        uz = fmaf(eav.x, w0.z, uz); uw = fmaf(eav.x, w0.w, uw);
        ux = fmaf(eav.y, w1.x, ux); uy = fmaf(eav.y, w1.y, uy);
        uz = fmaf(eav.y, w1.z, uz); uw = fmaf(eav.y, w1.w, uw);
        ux = fmaf(eav.z, w2.x, ux); uy = fmaf(eav.z, w2.y, uy);
        uz = fmaf(eav.z, w2.z, uz); uw = fmaf(eav.z, w2.w, uw);
        ux = fmaf(eav.w, w3.x, ux); uy = fmaf(eav.w, w3.y, uy);
        uz = fmaf(eav.w, w3.z, uz); uw = fmaf(eav.w, w3.w, uw);
        As[kc2 + 0][m] = prelu1(ux, ua);
        As[kc2 + 1][m] = prelu1(uy, ua);
        As[kc2 + 2][m] = prelu1(uz, ua);
        As[kc2 + 3][m] = prelu1(uw, ua);
      }
    }
    __syncthreads();
    kloop64(As, Ws, acc, r0, n0, n1);
    __syncthreads();
  }

  // Epilogue + run-accumulated scatter (rows are consecutive sorted edges).
  const float alpha = *alpha_ptr;
  const float4 bv0 = ld4(bvec + n0);
  const float4 bv1 = ld4(bvec + n1);
  int curd = -1;
  float4 sa = make_float4(0.f,0.f,0.f,0.f), sb = sa;
  #pragma unroll
  for (int i = 0; i < 8; ++i) {
    int ed = e0 + r0 + i;
    int d = (ed < E) ? sDst[ed] : -2;
    if (d >= 0) {
      int sr = sSrc[ed];
      const float* Pr = P + (size_t)d * 128;
      const float* Qr = Q + (size_t)sr * 128;
      float4 pv0 = ld4(Pr + n0), pv1 = ld4(Pr + n1);
      float4 qv0 = ld4(Qr + n0), qv1 = ld4(Qr + n1);
      float4 za, zb;
      za.x = prelu1(acc[i][0] + pv0.x + qv0.x + bv0.x, alpha);
      za.y = prelu1(acc[i][1] + pv0.y + qv0.y + bv0.y, alpha);
      za.z = prelu1(acc[i][2] + pv0.z + qv0.z + bv0.z, alpha);
      za.w = prelu1(acc[i][3] + pv0.w + qv0.w + bv0.w, alpha);
      zb.x = prelu1(acc[i][4] + pv1.x + qv1.x + bv1.x, alpha);
      zb.y = prelu1(acc[i][5] + pv1.y + qv1.y + bv1.y, alpha);
      zb.z = prelu1(acc[i][6] + pv1.z + qv1.z + bv1.z, alpha);
      zb.w = prelu1(acc[i][7] + pv1.w + qv1.w + bv1.w, alpha);
      if (d == curd) {
        sa.x += za.x; sa.y += za.y; sa.z += za.z; sa.w += za.w;
        sb.x += zb.x; sb.y += zb.y; sb.z += zb.z; sb.w += zb.w;
      } else {
        if (curd >= 0) flush8(S, curd, n0, n1, sa, sb);
        curd = d; sa = za; sb = zb;
      }
    } else {
      if (curd >= 0) flush8(S, curd, n0, n1, sa, sb);
      curd = -1;
    }
  }
  if (curd >= 0) flush8(S, curd, n0, n1, sa, sb);
}

// Fused node-update: V = prelu(S@Wtil + h@Wn1a + ln_b1 + deg*btil, ln_a);
//                    h += V@ln_w2 + ln_b2   (V staged via LDS, never global)
__global__ __launch_bounds__(256, 2) void k_svu(
    const float* __restrict__ Sbuf, float* __restrict__ h,
    const float* __restrict__ Wtil_l, const float* __restrict__ Wn1a,
    const float* __restrict__ ln_b1_l, const float* __restrict__ btil_l,
    const int* __restrict__ deg, const float* __restrict__ ln_a_l,
    const float* __restrict__ ln_w2_l, const float* __restrict__ ln_b2_l, int M)
{
  __shared__ float As[64][132];
  __shared__ float Ws[64][128];
  const int t = threadIdx.x;
  const int row0 = blockIdx.x * 128;
  float acc[8][8];
  #pragma unroll
  for (int i = 0; i < 8; ++i)
    #pragma unroll
    for (int j = 0; j < 8; ++j) acc[i][j] = 0.f;
  for (int c = 0; c < 2; ++c) gemm_chunk(Sbuf, Wtil_l, c, row0, M, t, As, Ws, acc);
  for (int c = 0; c < 2; ++c) gemm_chunk(h,    Wn1a,   c, row0, M, t, As, Ws, acc);

  const int r0 = (t >> 4) * 8, n0 = (t & 15) * 4, n1 = 64 + n0;
  const float alpha = *ln_a_l;
  const float4 b10 = ld4(ln_b1_l + n0), b11 = ld4(ln_b1_l + n1);
  const float4 bt0 = ld4(btil_l + n0), bt1 = ld4(btil_l + n1);
  #pragma unroll
  for (int i = 0; i < 8; ++i) {
    int gr = row0 + r0 + i;
    float degf = (gr < M) ? (float)deg[gr] : 0.f;
    acc[i][0] = prelu1(acc[i][0] + b10.x + degf * bt0.x, alpha);
    acc[i][1] = prelu1(acc[i][1] + b10.y + degf * bt0.y, alpha);
    acc[i][2] = prelu1(acc[i][2] + b10.z + degf * bt0.z, alpha);
    acc[i][3] = prelu1(acc[i][3] + b10.w + degf * bt0.w, alpha);
    acc[i][4] = prelu1(acc[i][4] + b11.x + degf * bt1.x, alpha);
    acc[i][5] = prelu1(acc[i][5] + b11.y + degf * bt1.y, alpha);
    acc[i][6] = prelu1(acc[i][6] + b11.z + degf * bt1.z, alpha);
    acc[i][7] = prelu1(acc[i][7] + b11.w + degf * bt1.w, alpha);
  }

  // second GEMM: h += V@ln_w2 ; V chunk staged transposed into As
  float acc2[8][8];
  #pragma unroll
  for (int i = 0; i < 8; ++i)
    #pragma unroll
    for (int j = 0; j < 8; ++j) acc2[i][j] = 0.f;
  for (int c = 0; c < 2; ++c) {
    #pragma unroll
    for (int it = 0; it < 8; ++it) {
      int idx = it * 256 + t;
      int k = idx >> 5, nc = (idx & 31) << 2;
      st4(&Ws[k][nc], ld4(ln_w2_l + (size_t)(c * 64 + k) * 128 + nc));
    }
    #pragma unroll
    for (int q = 0; q < 4; ++q) {
      int j = c * 4 + q;
      st4(&As[n0 + q][r0],
          make_float4(acc[0][j], acc[1][j], acc[2][j], acc[3][j]));
      st4(&As[n0 + q][r0 + 4],
          make_float4(acc[4][j], acc[5][j], acc[6][j], acc[7][j]));
    }
    __syncthreads();
    kloop64(As, Ws, acc2, r0, n0, n1);
    __syncthreads();
  }

  const float4 b20 = ld4(ln_b2_l + n0), b21 = ld4(ln_b2_l + n1);
  #pragma unroll
  for (int i = 0; i < 8; ++i) {
    int gr = row0 + r0 + i;
    if (gr >= M) continue;
    float* hp = h + (size_t)gr * 128;
    float4 h0 = ld4(hp + n0), h1 = ld4(hp + n1);
    h0.x += acc2[i][0] + b20.x; h0.y += acc2[i][1] + b20.y;
    h0.z += acc2[i][2] + b20.z; h0.w += acc2[i][3] + b20.w;
    h1.x += acc2[i][4] + b21.x; h1.y += acc2[i][5] + b21.y;
    h1.z += acc2[i][6] + b21.z; h1.w += acc2[i][7] + b21.w;
    st4(hp + n0, h0); st4(hp + n1, h1);
  }
}

// Fused decoder: out = prelu(h@de_w1+de_b1, de_a)@de_w2 + de_b2
__global__ __launch_bounds__(256, 2) void k_dec(
    const float* __restrict__ h, const float* __restrict__ de_w1,
    const float* __restrict__ de_b1, const float* __restrict__ de_a,
    const float* __restrict__ de_w2, const float* __restrict__ de_b2,
    float* __restrict__ out, int M)
{
  __shared__ float As[64][132];
  __shared__ float Ws[64][128];
  __shared__ float w2s[384];
  const int t = threadIdx.x;
  const int row0 = blockIdx.x * 128;
  for (int i = t; i < 384; i += 256) w2s[i] = de_w2[i];
  float acc[8][8];
  #pragma unroll
  for (int i = 0; i < 8; ++i)
    #pragma unroll
    for (int j = 0; j < 8; ++j) acc[i][j] = 0.f;
  for (int c = 0; c < 2; ++c) gemm_chunk(h, de_w1, c, row0, M, t, As, Ws, acc);

  const int r0 = (t >> 4) * 8, n0 = (t & 15) * 4;
  const float alpha = *de_a;
  const float4 b0 = ld4(de_b1 + n0), b1 = ld4(de_b1 + 64 + n0);
  #pragma unroll
  for (int i = 0; i < 8; ++i) {
    acc[i][0] = prelu1(acc[i][0] + b0.x, alpha);
    acc[i][1] = prelu1(acc[i][1] + b0.y, alpha);
    acc[i][2] = prelu1(acc[i][2] + b0.z, alpha);
    acc[i][3] = prelu1(acc[i][3] + b0.w, alpha);
    acc[i][4] = prelu1(acc[i][4] + b1.x, alpha);
    acc[i][5] = prelu1(acc[i][5] + b1.y, alpha);
    acc[i][6] = prelu1(acc[i][6] + b1.z, alpha);
    acc[i][7] = prelu1(acc[i][7] + b1.w, alpha);
  }
  float s0 = 0.f, s1 = 0.f, s2 = 0.f;
  for (int c = 0; c < 2; ++c) {
    #pragma unroll
    for (int q = 0; q < 4; ++q) {
      int j = c * 4 + q;
      st4(&As[n0 + q][r0],
          make_float4(acc[0][j], acc[1][j], acc[2][j], acc[3][j]));
      st4(&As[n0 + q][r0 + 4],
          make_float4(acc[4][j], acc[5][j], acc[6][j], acc[7][j]));
    }
    __syncthreads();
    if (t < 128) {
      for (int k = 0; k < 64; ++k) {
        float vv = As[k][t];
        s0 = fmaf(vv, w2s[(c * 64 + k) * 3 + 0], s0);
        s1 = fmaf(vv, w2s[(c * 64 + k) * 3 + 1], s1);
        s2 = fmaf(vv, w2s[(c * 64 + k) * 3 + 2], s2);
      }
    }
    __syncthreads();
  }
  if (t < 128) {
    int gr = row0 + t;
    if (gr < M) {
      out[(size_t)gr * 3 + 0] = s0 + de_b2[0];
      out[(size_t)gr * 3 + 1] = s1 + de_b2[1];
      out[(size_t)gr * 3 + 2] = s2 + de_b2[2];
    }
  }
}

// --------- folded-weight precompute (once per call, tiny) -------------------
__global__ __launch_bounds__(256) void k_prep(
    const float* __restrict__ ee_w2, const float* __restrict__ ee_b2,
    const float* __restrict__ le_w1, const float* __restrict__ le_b1,
    const float* __restrict__ le_w2, const float* __restrict__ le_b2,
    const float* __restrict__ ln_w1,
    float* __restrict__ What, float* __restrict__ Wtil,
    float* __restrict__ bvec, float* __restrict__ btil)
{
  const int l = blockIdx.x;
  const int which = blockIdx.y;
  const float* L; const float* Rm; const float* lb; const float* badd;
  float* Wout; float* bout;
  if (which == 0) {
    L = ee_w2; Rm = le_w1 + (size_t)l * 384 * 128 + 256 * 128;
    lb = ee_b2; badd = le_b1 + l * 128;
    Wout = What + l * 16384; bout = bvec + l * 128;
  } else {
    L = le_w2 + (size_t)l * 16384; Rm = ln_w1 + (size_t)l * 256 * 128 + 128 * 128;
    lb = le_b2 + l * 128; badd = nullptr;
    Wout = Wtil + l * 16384; bout = btil + l * 128;
  }
  const int t = threadIdx.x;
  for (int eidx = t; eidx < 16384; eidx += 256) {
    int k = eidx >> 7, n = eidx & 127;
    float a = 0.f;
    for (int d = 0; d < 128; d += 4) {
      float4 lv = ld4(L + k * 128 + d);
      a = fmaf(lv.x, Rm[(d + 0) * 128 + n], a);
      a = fmaf(lv.y, Rm[(d + 1) * 128 + n], a);
      a = fmaf(lv.z, Rm[(d + 2) * 128 + n], a);
      a = fmaf(lv.w, Rm[(d + 3) * 128 + n], a);
    }
    Wout[eidx] = a;
  }
  if (t < 128) {
    float a = badd ? badd[t] : 0.f;
    for (int d = 0; d < 128; ++d) a = fmaf(lb[d], Rm[d * 128 + t], a);
    bout[t] = a;
  }
}

// First node-encoder layer: UN = prelu(x@ne_w1 + ne_b1)
__global__ __launch_bounds__(256) void k_node_u(
    const float* __restrict__ x, const float* __restrict__ w1,
    const float* __restrict__ b1, const float* __restrict__ a_ptr,
    float* __restrict__ U, int M)
{
  int gid = blockIdx.x * 256 + threadIdx.x;
  int m = gid >> 5;
  if (m >= M) return;
  int nc = (gid & 31) << 2;
  float a = *a_ptr;
  float4 bb = ld4(b1 + nc);
  float z0 = bb.x, z1 = bb.y, z2 = bb.z, z3 = bb.w;
  const float* xr = x + (size_t)m * 30;
  #pragma unroll
  for (int j = 0; j < 30; ++j) {
    float xv = xr[j];
    float4 wv = ld4(w1 + j * 128 + nc);
    z0 = fmaf(xv, wv.x, z0); z1 = fmaf(xv, wv.y, z1);
    z2 = fmaf(xv, wv.z, z2); z3 = fmaf(xv, wv.w, z3);
  }
  st4(U + (size_t)m * 128 + nc,
      make_float4(prelu1(z0, a), prelu1(z1, a), prelu1(z2, a), prelu1(z3, a)));
}

// --------- counting sort by dst ---------------------------------------------
__global__ void k_hist(const int* __restrict__ dstIdx, int* __restrict__ deg, int E) {
  int i = blockIdx.x * 256 + threadIdx.x;
  if (i < E) atomicAdd(deg + dstIdx[i], 1);
}

__global__ __launch_bounds__(1024) void k_scan(
    const int* __restrict__ deg, int* __restrict__ cursor, int N, int per)
{
  __shared__ int part[1024];
  const int t = threadIdx.x;
  const int base = t * per;
  int local = 0;
  for (int i = 0; i < per; ++i) {
    int idx = base + i;
    if (idx < N) local += deg[idx];
  }
  part[t] = local;
  __syncthreads();
  for (int off = 1; off < 1024; off <<= 1) {
    int v = (t >= off) ? part[t - off] : 0;
    __syncthreads();
    part[t] += v;
    __syncthreads();
  }
  int run = (t == 0) ? 0 : part[t - 1];
  for (int i = 0; i < per; ++i) {
    int idx = base + i;
    if (idx < N) { cursor[idx] = run; run += deg[idx]; }
  }
}

__global__ void k_scatter(const int* __restrict__ srcIdx, const int* __restrict__ dstIdx,
                          const float* __restrict__ ea, int* __restrict__ cursor,
                          int* __restrict__ sSrc, int* __restrict__ sDst,
                          float* __restrict__ sEa, int E)
{
  int e = blockIdx.x * 256 + threadIdx.x;
  if (e < E) {
    int d = dstIdx[e];
    int p = atomicAdd(cursor + d, 1);
    sSrc[p] = srcIdx[e];
    sDst[p] = d;
    st4(sEa + (size_t)p * 4, ld4(ea + (size_t)e * 4));
  }
}

// ---------------------------------------------------------------------------
extern "C" void kernel_launch(void* const* d_in, const int* in_sizes, int n_in,
                              void* d_out, int out_size, void* d_ws, size_t ws_size,
                              hipStream_t stream)
{
  const float* x     = (const float*)d_in[0];
  const float* ea    = (const float*)d_in[1];
  const int*   ei    = (const int*)  d_in[2];
  const float* ne_w1 = (const float*)d_in[3];
  const float* ne_b1 = (const float*)d_in[4];
  const float* ne_a  = (const float*)d_in[5];
  const float* ne_w2 = (const float*)d_in[6];
  const float* ne_b2 = (const float*)d_in[7];
  const float* ee_w1 = (const float*)d_in[8];
  const float* ee_b1 = (const float*)d_in[9];
  const float* ee_a  = (const float*)d_in[10];
  const float* ee_w2 = (const float*)d_in[11];
  const float* ee_b2 = (const float*)d_in[12];
  const float* le_w1 = (const float*)d_in[13];
  const float* le_b1 = (const float*)d_in[14];
  const float* le_a  = (const float*)d_in[15];
  const float* le_w2 = (const float*)d_in[16];
  const float* le_b2 = (const float*)d_in[17];
  const float* ln_w1 = (const float*)d_in[18];
  const float* ln_b1 = (const float*)d_in[19];
  const float* ln_a  = (const float*)d_in[20];
  const float* ln_w2 = (const float*)d_in[21];
  const float* ln_b2 = (const float*)d_in[22];
  const float* de_w1 = (const float*)d_in[23];
  const float* de_b1 = (const float*)d_in[24];
  const float* de_a  = (const float*)d_in[25];
  const float* de_w2 = (const float*)d_in[26];
  const float* de_b2 = (const float*)d_in[27];

  const int N = in_sizes[0] / 30;
  const int E = in_sizes[1] / 4;
  const int* srcIdx = ei;        // edge_index[0] = x_j (source)
  const int* dstIdx = ei + E;    // edge_index[1] = x_i (target / agg index)

  float* w = (float*)d_ws;
  const size_t NN = (size_t)N * 128;
  float* h    = w; w += NN;
  float* Pb   = w; w += NN;
  float* Qb   = w; w += NN;
  float* Sb   = w; w += NN;       // S buffer; also UN before the layer loop
  float* What = w; w += 5 * 16384;
  float* Wtil = w; w += 5 * 16384;
  float* bvec = w; w += 5 * 128;
  float* btil = w; w += 5 * 128;
  float* sEa  = w; w += (size_t)E * 4;
  int* ip     = (int*)w;
  int* deg    = ip; ip += N;
  int* cursor = ip; ip += N;
  int* sSrc   = ip; ip += E;
  int* sDst   = ip; ip += E;

  float* out = (float*)d_out;
  const int gN = (N + 127) / 128;
  const int gE = (E + 127) / 128;

  k_prep<<<dim3(5, 2), dim3(256), 0, stream>>>(ee_w2, ee_b2, le_w1, le_b1,
                                               le_w2, le_b2, ln_w1,
                                               What, Wtil, bvec, btil);
  // counting sort of edges by dst
  hipMemsetAsync(deg, 0, (size_t)N * 4, stream);
  k_hist<<<dim3((E + 255) / 256), dim3(256), 0, stream>>>(dstIdx, deg, E);
  k_scan<<<dim3(1), dim3(1024), 0, stream>>>(deg, cursor, N, (N + 1023) / 1024);
  k_scatter<<<dim3((E + 255) / 256), dim3(256), 0, stream>>>(
      srcIdx, dstIdx, ea, cursor, sSrc, sDst, sEa, E);

  // node encoder: UN (in Sb) -> h
  k_node_u<<<dim3((N * 32 + 255) / 256), dim3(256), 0, stream>>>(x, ne_w1, ne_b1, ne_a, Sb, N);
  k_gemm<true, false><<<dim3(gN), dim3(256), 0, stream>>>(
      Sb, ne_w2, h, ne_b2, nullptr, N);

  for (int l = 0; l < 5; ++l) {
    k_pq<<<dim3(gN, 2), dim3(256), 0, stream>>>(
        h, le_w1 + (size_t)l * 49152, Pb, Qb, N);
    hipMemsetAsync(Sb, 0, NN * 4, stream);
    k_edge<<<dim3(gE), dim3(256), 0, stream>>>(
        sEa, sSrc, sDst, ee_w1, ee_b1, ee_a,
        What + l * 16384, bvec + l * 128, le_a + l, Pb, Qb, Sb, E);
    k_svu<<<dim3(gN), dim3(256), 0, stream>>>(
        Sb, h, Wtil + l * 16384, ln_w1 + (size_t)l * 32768,
        ln_b1 + (size_t)l * 128, btil + l * 128, deg, ln_a + l,
        ln_w2 + (size_t)l * 16384, ln_b2 + (size_t)l * 128, N);
  }

  k_dec<<<dim3(gN), dim3(256), 0, stream>>>(h, de_w1, de_b1, de_a, de_w2, de_b2, out, N);
}